// Round 2
// baseline (486.738 us; speedup 1.0000x reference)
//
#include <hip/hip_runtime.h>

// SparseSpikingConv2D — Round 8: pipeline the R7 MFMA conv.
// R7 post-mortem: convM 243 us with MfmaUtil 9.6 / VALUBusy 10.9 / HBM 13% --
// latency-bound: per-block serial stage->barrier->compute->epilogue exposed
// ~900-cy HBM latency everywhere (wave stall ~97%). R8: 4 y-rows per block
// (grid 512 = 2/CU, no tail), 3-slot LDS row ring, T14 issue-early/write-late
// x prefetch + mem prefetch under the 2100-cy MFMA loop. MFMA core, swizzle,
// epilogue math, flagging, prep, fixB unchanged (bitwise-same results).

typedef _Float16 half8 __attribute__((ext_vector_type(8)));
typedef float f32x4 __attribute__((ext_vector_type(4)));

constexpr int CIc = 64, COc = 128, HHc = 64, WWc = 64, NBc = 32;
constexpr float EPSB = 2e-4f;        // borderline band on mthr
constexpr unsigned CAPc = 1u << 18;  // fixup list capacity (~13K observed)

// workspace layout (bytes)
constexpr size_t O_CNT   = 0;                    // 1 uint (padded 16)
constexpr size_t O_NORMD = 16;                   // 128 double
constexpr size_t O_RNORM = O_NORMD + 1024;       // 128 float
constexpr size_t O_WDT   = O_RNORM + 512;        // [co][t][ci] double = 589824 B
constexpr size_t O_WHI   = O_WDT + 589824;       // [t][co][ci] fp16 hi = 147456 B
constexpr size_t O_WLO   = O_WHI + 147456;       // [t][co][ci] fp16 lo = 147456 B
constexpr size_t O_LIST  = O_WLO + 147456;       // CAPc uint
constexpr size_t WS_NEED = O_LIST + (size_t)CAPc * 4;   // ~1.85 MB

// Fused prep: blocks 0..127 -> norm (co=bx, 64-lane fp64 butterfly);
// blocks 128..415 -> wdT (fp64, for fixB) + whi/wlo (fp16 split, for convM).
__global__ void prep_kernel(const float* __restrict__ w, double* __restrict__ normd,
                            float* __restrict__ rnormf, double* __restrict__ wdT,
                            _Float16* __restrict__ whi, _Float16* __restrict__ wlo,
                            unsigned* __restrict__ counter) {
    const int bx = blockIdx.x;
    if (bx < 128) {
        const int co = bx, lane = threadIdx.x & 63;
        if (threadIdx.x >= 64) return;
        double s = 0.0;
        #pragma unroll
        for (int k = 0; k < 9; ++k) {
            const double v = (double)w[(k * 64 + lane) * COc + co];
            s = fma(v, v, s);
        }
        #pragma unroll
        for (int off = 32; off; off >>= 1) s += __shfl_xor(s, off);
        if (lane == 0) {
            s += 1e-8;
            normd[co]  = s;
            rnormf[co] = (float)(1.0 / s);
            if (co == 0) counter[0] = 0u;
        }
    } else {
        const int i = (bx - 128) * 256 + threadIdx.x;  // over 73728
        if (i >= 9 * CIc * COc) return;
        const int ci = i & 63, t = (i >> 6) % 9, co = i / (9 * 64);
        const float v = w[(t * CIc + ci) * COc + co];
        wdT[i] = (double)v;                            // wdT[co][t][ci]
        if (whi) {
            const int i2 = (t * COc + co) * CIc + ci;  // [t][co][ci]
            const _Float16 h = (_Float16)v;
            whi[i2] = h;
            wlo[i2] = (_Float16)(v - (float)h);
        }
    }
}

// ---- Pass A (MFMA, pipelined): 4 y-rows per block, 3-slot LDS row ring ----
// Block = 256 thr = 4 waves; grid (16, 32) = 512 blocks = 2/CU exactly.
// Per output row j (y=y0+j): inputs rows y-1..y+1 live in slots
// (j+dy)%3; retired slot j%3 is rewritten with row y+2 after the
// post-compute barrier (x data was loaded into regs one phase earlier).
// A-frag: lane&15=co, k=(lane>>4)*8+j (global, L2-hot). B-frag: lane&15=px,
// ds_read_b128 XOR-swizzled (byte ^= (px1&7)<<4, write and read). D: row=co=
// (lane>>4)*4+r, col=px=lane&15. Wave wv owns couts [wv*32, wv*32+32).
__global__ __launch_bounds__(256, 2) void convM(
    const float* __restrict__ x,       // [32,64,64,64]
    const float* __restrict__ mem,     // [32,128,64,64]
    const _Float16* __restrict__ whi,  // [9,128,64]
    const _Float16* __restrict__ wlo,  // [9,128,64]
    const float* __restrict__ beta_p,
    const float* __restrict__ bias,
    const float* __restrict__ rnormf,
    float* __restrict__ out_spk, float* __restrict__ out_mem,
    unsigned* __restrict__ counter, unsigned* __restrict__ list)
{
    __shared__ _Float16 xs[2][3 * 66 * 64];   // [hi/lo][slot*66+px1][ci] = 49.5 KB

    const int tid = threadIdx.x;
    const int y0 = blockIdx.x * 4, n = blockIdx.y;

    char* xs0w = (char*)(&xs[0][0]);
    char* xs1w = (char*)(&xs[1][0]);

    // ---- row staging helpers: 528 items (8 cig x 66 px1), <=3 per thread ----
    float xr[3][8];   // in-flight x row (floats), static-indexed only

    auto issueRow = [&](int rabs) {            // global -> xr (issue loads)
        #pragma unroll
        for (int k = 0; k < 3; ++k) {
            const int it = tid + k * 256;
            if (it < 528) {
                const int px1 = it % 66, cig = it / 66;
                const bool v = (px1 >= 1) && (px1 <= 64) && (rabs >= 0) && (rabs < HHc);
                const float* xp = x + (((size_t)n * CIc + cig * 8) * HHc + (v ? rabs : 0)) * WWc
                                    + (v ? (px1 - 1) : 0);
                #pragma unroll
                for (int jj = 0; jj < 8; ++jj)
                    xr[k][jj] = v ? xp[jj * (HHc * WWc)] : 0.0f;
            }
        }
    };
    auto writeRow = [&](int sl) {              // xr -> hi/lo halves -> LDS slot
        #pragma unroll
        for (int k = 0; k < 3; ++k) {
            const int it = tid + k * 256;
            if (it < 528) {
                const int px1 = it % 66, cig = it / 66;
                half8 hv, lv;
                #pragma unroll
                for (int jj = 0; jj < 8; ++jj) {
                    const float v = xr[k][jj];
                    const _Float16 h = (_Float16)v;
                    hv[jj] = h;
                    lv[jj] = (_Float16)(v - (float)h);
                }
                const unsigned off = (unsigned)(sl * 66 + px1) * 128
                                   + (((unsigned)cig * 16) ^ (((unsigned)px1 & 7) << 4));
                *(half8*)(xs0w + off) = hv;
                *(half8*)(xs1w + off) = lv;
            }
        }
    };

    // ---- prologue: stage input rows y0-1, y0, y0+1 into slots 0,1,2 ----
    #pragma unroll
    for (int sl = 0; sl < 3; ++sl) {
        issueRow(y0 - 1 + sl);
        writeRow(sl);
    }
    issueRow(y0 + 2);     // in-flight for j=0's write phase
    __syncthreads();

    // ---- compute setup ----
    const int lane   = tid & 63;
    const int wv     = tid >> 6;
    const int co0    = wv * 32;
    const int lanelo = lane & 15;
    const unsigned kg2 = (unsigned)((lane >> 4) * 16);

    const _Float16* wh_l = whi + (size_t)(co0 + lanelo) * 64 + (lane >> 4) * 8;
    const _Float16* wl_l = wlo + (size_t)(co0 + lanelo) * 64 + (lane >> 4) * 8;
    const char* xs0 = (const char*)(&xs[0][0]);
    const char* xs1 = (const char*)(&xs[1][0]);

    const float beta = beta_p[0];
    const float omb  = 1.0f - beta;

    int s0 = 0, s1 = 1, s2 = 2;   // slots of input rows y-1, y, y+1

    for (int j = 0; j < 4; ++j) {
        const int y = y0 + j;

        // -- prefetch mem[] for this row (consumed in epilogue, ~2100cy away) --
        float mv[2][4][4];
        #pragma unroll
        for (int cf = 0; cf < 2; ++cf)
            #pragma unroll
            for (int pf = 0; pf < 4; ++pf)
                #pragma unroll
                for (int r = 0; r < 4; ++r) {
                    const int co = co0 + cf * 16 + (lane >> 4) * 4 + r;
                    mv[cf][pf][r] =
                        mem[(((size_t)n * COc + co) * HHc + y) * WWc + pf * 16 + lanelo];
                }

        // -- MFMA main loop (identical math/order to R7) --
        f32x4 acc[2][4];
        #pragma unroll
        for (int a = 0; a < 2; ++a)
            #pragma unroll
            for (int b = 0; b < 4; ++b) acc[a][b] = f32x4{0.f, 0.f, 0.f, 0.f};

        const unsigned rbase[3] = {(unsigned)s0 * 8448, (unsigned)s1 * 8448,
                                   (unsigned)s2 * 8448};

        #pragma unroll
        for (int t = 0; t < 9; ++t) {
            const int dy = t / 3, dx = t % 3;
            unsigned rb[4], sz[4];
            #pragma unroll
            for (int pf = 0; pf < 4; ++pf) {
                const int px1 = pf * 16 + lanelo + dx;
                rb[pf] = rbase[dy] + (unsigned)px1 * 128;
                sz[pf] = ((unsigned)px1 & 7) << 4;
            }
            #pragma unroll
            for (int cs = 0; cs < 2; ++cs) {
                const half8 ah0 = *(const half8*)(wh_l + t * 8192 + 0 * 1024 + cs * 32);
                const half8 ah1 = *(const half8*)(wh_l + t * 8192 + 1 * 1024 + cs * 32);
                const half8 al0 = *(const half8*)(wl_l + t * 8192 + 0 * 1024 + cs * 32);
                const half8 al1 = *(const half8*)(wl_l + t * 8192 + 1 * 1024 + cs * 32);
                #pragma unroll
                for (int pf = 0; pf < 4; ++pf) {
                    const unsigned ob = rb[pf] + (((unsigned)cs * 64 + kg2) ^ sz[pf]);
                    const half8 bh = *(const half8*)(xs0 + ob);
                    const half8 bl = *(const half8*)(xs1 + ob);
                    acc[0][pf] = __builtin_amdgcn_mfma_f32_16x16x32_f16(ah0, bh, acc[0][pf], 0, 0, 0);
                    acc[0][pf] = __builtin_amdgcn_mfma_f32_16x16x32_f16(ah0, bl, acc[0][pf], 0, 0, 0);
                    acc[0][pf] = __builtin_amdgcn_mfma_f32_16x16x32_f16(al0, bh, acc[0][pf], 0, 0, 0);
                    acc[1][pf] = __builtin_amdgcn_mfma_f32_16x16x32_f16(ah1, bh, acc[1][pf], 0, 0, 0);
                    acc[1][pf] = __builtin_amdgcn_mfma_f32_16x16x32_f16(ah1, bl, acc[1][pf], 0, 0, 0);
                    acc[1][pf] = __builtin_amdgcn_mfma_f32_16x16x32_f16(al1, bh, acc[1][pf], 0, 0, 0);
                }
            }
        }

        __syncthreads();           // all waves done reading retired slot s0

        if (j < 3) writeRow(s0);   // row y+2 -> slot s0 (xr loads long arrived)
        __syncthreads();           // writes visible before next compute

        // -- issue next in-flight x row during epilogue + next compute --
        if (j < 2) issueRow(y0 + j + 3);

        // -- epilogue: LIF + spike + borderline flagging (mv prefetched) --
        #pragma unroll
        for (int cf = 0; cf < 2; ++cf) {
            #pragma unroll
            for (int r = 0; r < 4; ++r) {
                const int co = co0 + cf * 16 + (lane >> 4) * 4 + r;
                const float rn = rnormf[co];
                const float bi = bias[co];
                #pragma unroll
                for (int pf = 0; pf < 4; ++pf) {
                    const int px = pf * 16 + lanelo;
                    const size_t idx = (((size_t)n * COc + co) * HHc + y) * WWc + px;
                    const float nm   = fmaf(mv[cf][pf][r], beta, acc[cf][pf][r] * omb);
                    const float mthr = fmaf(nm, rn, -bi);
                    const int s = (mthr > 0.f) + (mthr > 1.f) + (mthr > 2.f) + (mthr > 3.f);
                    out_spk[idx] = (float)s;
                    out_mem[idx] = (s > 0) ? 0.0f : nm;

                    const bool fl = (fabsf(mthr) < EPSB) | (fabsf(mthr - 1.f) < EPSB) |
                                    (fabsf(mthr - 2.f) < EPSB) | (fabsf(mthr - 3.f) < EPSB);
                    const unsigned long long msk = __ballot(fl);
                    if (msk) {
                        unsigned wb = 0;
                        if (lane == 0) wb = atomicAdd(counter, (unsigned)__popcll(msk));
                        wb = __shfl(wb, 0);
                        if (fl) {
                            const unsigned pos =
                                wb + (unsigned)__popcll(msk & ((1ull << lane) - 1ull));
                            if (pos < CAPc) list[pos] = (unsigned)idx;
                        }
                    }
                }
            }
        }

        // rotate ring: slots of rows y, y+1, y+2 become y-1', y', y+1'
        const int tmpS = s0; s0 = s1; s1 = s2; s2 = tmpS;
    }
}

// ---- Pass B: exact fp64 recompute of flagged pixels (wave per pixel, lane=ci) ----
__global__ __launch_bounds__(256) void fixB(
    const float* __restrict__ x, const float* __restrict__ mem,
    const float* __restrict__ beta_p, const float* __restrict__ bias,
    const double* __restrict__ normd, const double* __restrict__ wdT,
    const unsigned* __restrict__ counter, const unsigned* __restrict__ list,
    float* __restrict__ out_spk, float* __restrict__ out_mem)
{
    const int lane  = threadIdx.x & 63;
    const int wave  = blockIdx.x * 4 + (threadIdx.x >> 6);
    const int nwave = gridDim.x * 4;
    const unsigned cnt = min(counter[0], CAPc);
    const double beta = (double)beta_p[0];
    const double omb  = 1.0 - beta;

    for (unsigned p = wave; p < cnt; p += nwave) {
        const unsigned idx = list[p];
        const int xp = idx & 63, yp = (idx >> 6) & 63;
        const int co = (idx >> 12) & 127, n = idx >> 19;

        const float*  xc = x + ((size_t)n * CIc + lane) * (HHc * WWc);
        const double* wt = wdT + (size_t)co * 9 * CIc + lane;

        double a = 0.0;
        #pragma unroll
        for (int t = 0; t < 9; ++t) {
            const int yy = yp + t / 3 - 1, xx = xp + t % 3 - 1;
            const bool v = ((unsigned)yy < 64u) && ((unsigned)xx < 64u);
            const int yyc = min(max(yy, 0), 63), xxc = min(max(xx, 0), 63);
            const double xv = v ? (double)xc[yyc * WWc + xxc] : 0.0;
            a = fma(xv, wt[t * CIc], a);
        }
        #pragma unroll
        for (int off = 32; off; off >>= 1) a += __shfl_xor(a, off);

        if (lane == 0) {
            const double nm   = (double)mem[idx] * beta + a * omb;
            const double mthr = nm / normd[co] - (double)bias[co];
            const int s = (mthr > 0.) + (mthr > 1.) + (mthr > 2.) + (mthr > 3.);
            out_spk[idx] = (float)s;
            out_mem[idx] = (s > 0) ? 0.0f : (float)nm;
        }
    }
}

// ---- Fallback (ws too small): all-fp64 direct conv ----
__global__ __launch_bounds__(256) void conv_fp64_fb(
    const float* __restrict__ x, const float* __restrict__ mem,
    const float* __restrict__ w, const float* __restrict__ beta_p,
    const float* __restrict__ bias, const double* __restrict__ normd,
    float* __restrict__ out_spk, float* __restrict__ out_mem)
{
    const int ix = threadIdx.x, iy = blockIdx.x * 4 + threadIdx.y;
    const int co0 = blockIdx.y * 8, n = blockIdx.z;
    bool valid[9]; int xoff[9];
    #pragma unroll
    for (int kh = 0; kh < 3; ++kh) {
        const int yy = iy + kh - 1;
        #pragma unroll
        for (int kw = 0; kw < 3; ++kw) {
            const int xx = ix + kw - 1, t = kh * 3 + kw;
            valid[t] = ((unsigned)yy < 64u) && ((unsigned)xx < 64u);
            xoff[t]  = yy * WWc + xx;
        }
    }
    double acc[8];
    #pragma unroll
    for (int j = 0; j < 8; ++j) acc[j] = 0.0;
    const float* xb = x + (size_t)n * CIc * HHc * WWc;
    for (int ci = 0; ci < CIc; ++ci) {
        const float* xc = xb + (size_t)ci * HHc * WWc;
        #pragma unroll
        for (int t = 0; t < 9; ++t) {
            const double xv = valid[t] ? (double)xc[xoff[t]] : 0.0;
            const float* wt = w + ((size_t)t * CIc + ci) * COc + co0;
            #pragma unroll
            for (int j = 0; j < 8; ++j) acc[j] = fma(xv, (double)wt[j], acc[j]);
        }
    }
    const double beta = (double)beta_p[0], omb = 1.0 - beta;
    const size_t base = (((size_t)n * COc + co0) * HHc + iy) * WWc + ix;
    #pragma unroll
    for (int j = 0; j < 8; ++j) {
        const size_t idx = base + (size_t)j * (HHc * WWc);
        const double nm   = (double)mem[idx] * beta + acc[j] * omb;
        const double mthr = nm / normd[co0 + j] - (double)bias[co0 + j];
        const int s = (mthr > 0.) + (mthr > 1.) + (mthr > 2.) + (mthr > 3.);
        out_spk[idx] = (float)s;
        out_mem[idx] = (s > 0) ? 0.0f : (float)nm;
    }
}

extern "C" void kernel_launch(void* const* d_in, const int* in_sizes, int n_in,
                              void* d_out, int out_size, void* d_ws, size_t ws_size,
                              hipStream_t stream) {
    const float* x      = (const float*)d_in[0];
    const float* mem    = (const float*)d_in[1];
    const float* w      = (const float*)d_in[2];
    const float* beta_p = (const float*)d_in[3];
    const float* bias   = (const float*)d_in[4];

    float* out_spk = (float*)d_out;
    float* out_mem = out_spk + (size_t)NBc * COc * HHc * WWc;

    char* ws = (char*)d_ws;
    unsigned* counter = (unsigned*)(ws + O_CNT);
    double*   normd   = (double*)(ws + O_NORMD);
    float*    rnormf  = (float*)(ws + O_RNORM);
    double*   wdT     = (double*)(ws + O_WDT);
    _Float16* whi     = (_Float16*)(ws + O_WHI);
    _Float16* wlo     = (_Float16*)(ws + O_WLO);
    unsigned* list    = (unsigned*)(ws + O_LIST);

    if (ws_size >= WS_NEED) {
        prep_kernel<<<128 + 288, 256, 0, stream>>>(w, normd, rnormf, wdT, whi, wlo,
                                                   counter);
        dim3 grdM(HHc / 4, NBc, 1);        // 16 y-quads x 32 images = 512 blocks
        convM<<<grdM, 256, 0, stream>>>(x, mem, whi, wlo, beta_p, bias, rnormf,
                                        out_spk, out_mem, counter, list);
        fixB<<<512, 256, 0, stream>>>(x, mem, beta_p, bias, normd, wdT,
                                      counter, list, out_spk, out_mem);
    } else {
        prep_kernel<<<128, 256, 0, stream>>>(w, normd, rnormf, wdT, nullptr, nullptr,
                                             counter);
        dim3 blk(WWc, 4, 1);
        dim3 grd(HHc / 4, COc / 8, NBc);
        conv_fp64_fb<<<grd, blk, 0, stream>>>(x, mem, w, beta_p, bias, normd,
                                              out_spk, out_mem);
    }
}

// Round 3
// 484.206 us; speedup vs baseline: 1.0052x; 1.0052x over previous
//
#include <hip/hip_runtime.h>

// SparseSpikingConv2D — Round 9: R7 MFMA core, half-width tile for occupancy.
// R8 post-mortem: reg-buffered pipelining spilled (VGPR 68->128, FETCH 90->265MB,
// WRITE 160->268MB = scratch traffic), occupancy fell 29.5->21%, convM 243->282us.
// REVERT to R7 structure (proven 68 VGPR, no spill). R7 residual: latency-bound,
// MfmaUtil 9.6 / VALU 10.9 / HBM 13%, only ~2.4 blocks/CU resident (LDS 50688B
// caps at 3). R9: halve W-tile (32+2 halo px): LDS 26112B -> 6 blocks/CU = 24
// waves/CU, 4096 blocks. Per-pixel accumulation order identical to R7 ->
// bitwise-same results; TLP does the latency hiding, zero per-thread buffering.

typedef _Float16 half8 __attribute__((ext_vector_type(8)));
typedef float f32x4 __attribute__((ext_vector_type(4)));

constexpr int CIc = 64, COc = 128, HHc = 64, WWc = 64, NBc = 32;
constexpr float EPSB = 2e-4f;        // borderline band on mthr
constexpr unsigned CAPc = 1u << 18;  // fixup list capacity (~13K observed)

// workspace layout (bytes)
constexpr size_t O_CNT   = 0;                    // 1 uint (padded 16)
constexpr size_t O_NORMD = 16;                   // 128 double
constexpr size_t O_RNORM = O_NORMD + 1024;       // 128 float
constexpr size_t O_WDT   = O_RNORM + 512;        // [co][t][ci] double = 589824 B
constexpr size_t O_WHI   = O_WDT + 589824;       // [t][co][ci] fp16 hi = 147456 B
constexpr size_t O_WLO   = O_WHI + 147456;       // [t][co][ci] fp16 lo = 147456 B
constexpr size_t O_LIST  = O_WLO + 147456;       // CAPc uint
constexpr size_t WS_NEED = O_LIST + (size_t)CAPc * 4;   // ~1.85 MB

// Fused prep: blocks 0..127 -> norm (co=bx, 64-lane fp64 butterfly);
// blocks 128..415 -> wdT (fp64, for fixB) + whi/wlo (fp16 split, for convM).
__global__ void prep_kernel(const float* __restrict__ w, double* __restrict__ normd,
                            float* __restrict__ rnormf, double* __restrict__ wdT,
                            _Float16* __restrict__ whi, _Float16* __restrict__ wlo,
                            unsigned* __restrict__ counter) {
    const int bx = blockIdx.x;
    if (bx < 128) {
        const int co = bx, lane = threadIdx.x & 63;
        if (threadIdx.x >= 64) return;
        double s = 0.0;
        #pragma unroll
        for (int k = 0; k < 9; ++k) {
            const double v = (double)w[(k * 64 + lane) * COc + co];
            s = fma(v, v, s);
        }
        #pragma unroll
        for (int off = 32; off; off >>= 1) s += __shfl_xor(s, off);
        if (lane == 0) {
            s += 1e-8;
            normd[co]  = s;
            rnormf[co] = (float)(1.0 / s);
            if (co == 0) counter[0] = 0u;
        }
    } else {
        const int i = (bx - 128) * 256 + threadIdx.x;  // over 73728
        if (i >= 9 * CIc * COc) return;
        const int ci = i & 63, t = (i >> 6) % 9, co = i / (9 * 64);
        const float v = w[(t * CIc + ci) * COc + co];
        wdT[i] = (double)v;                            // wdT[co][t][ci]
        if (whi) {
            const int i2 = (t * COc + co) * CIc + ci;  // [t][co][ci]
            const _Float16 h = (_Float16)v;
            whi[i2] = h;
            wlo[i2] = (_Float16)(v - (float)h);
        }
    }
}

// ---- Pass A (MFMA): fp16-split implicit GEMM conv, half-width tile ----
// Block = 256 thr = 4 waves; one (n, y, W-half) per block; grid (64,2,32)=4096.
// LDS 26112 B -> 6 blocks/CU = 24 waves/CU resident.
// A-frag: lane&15 = co, k = ci = (lane>>4)*8+j  (global load, L2-hot)
// B-frag: lane&15 = px, k = ci  (ds_read_b128, XOR-swizzle byte^=(px1&7)<<4,
//         applied on BOTH write and read). D: row=co=(lane>>4)*4+r, col=px.
// Wave wv owns couts [wv*32, wv*32+32) x 32 px: acc = 2x2 frags = 16 VGPR.
__global__ __launch_bounds__(256, 2) void convM(
    const float* __restrict__ x,       // [32,64,64,64]
    const float* __restrict__ mem,     // [32,128,64,64]
    const _Float16* __restrict__ whi,  // [9,128,64]
    const _Float16* __restrict__ wlo,  // [9,128,64]
    const float* __restrict__ beta_p,
    const float* __restrict__ bias,
    const float* __restrict__ rnormf,
    float* __restrict__ out_spk, float* __restrict__ out_mem,
    unsigned* __restrict__ counter, unsigned* __restrict__ list)
{
    __shared__ _Float16 xs[2][3 * 34 * 64];   // [hi/lo][row*34+px1][ci] = 25.5 KB

    const int tid = threadIdx.x;
    const int y = blockIdx.x, px0 = blockIdx.y * 32, n = blockIdx.z;

    // ---- stage: 3 rows x 8 ci-groups x 34 px1 (px1=0..33 <-> px=px0-1..px0+32) ----
    for (int i = tid; i < 3 * 8 * 34; i += 256) {
        const int px1 = i % 34;
        const int q   = i / 34;
        const int cig = q & 7, row = q >> 3;
        const int yy  = y + row - 1;
        const int px  = px0 + px1 - 1;
        const bool valid = ((unsigned)px < 64u) && (yy >= 0) && (yy < HHc);
        const float* xp = x + (((size_t)n * CIc + cig * 8) * HHc + (valid ? yy : 0)) * WWc
                            + (valid ? px : 0);
        half8 hv, lv;
        #pragma unroll
        for (int j = 0; j < 8; ++j) {
            const float v = valid ? xp[j * (HHc * WWc)] : 0.0f;
            const _Float16 h = (_Float16)v;
            hv[j] = h;
            lv[j] = (_Float16)(v - (float)h);
        }
        const unsigned off = (unsigned)(row * 34 + px1) * 128
                           + (((unsigned)cig * 16) ^ (((unsigned)px1 & 7) << 4));
        *(half8*)((char*)(&xs[0][0]) + off) = hv;
        *(half8*)((char*)(&xs[1][0]) + off) = lv;
    }
    __syncthreads();

    // ---- compute ----
    const int lane   = tid & 63;
    const int wv     = tid >> 6;          // 0..3 -> cout range
    const int co0    = wv * 32;
    const int lanelo = lane & 15;
    const unsigned kg2 = (unsigned)((lane >> 4) * 16);  // byte offset of k-group

    f32x4 acc[2][2];
    #pragma unroll
    for (int a = 0; a < 2; ++a)
        #pragma unroll
        for (int b = 0; b < 2; ++b) acc[a][b] = f32x4{0.f, 0.f, 0.f, 0.f};

    const _Float16* wh_l = whi + (size_t)(co0 + lanelo) * 64 + (lane >> 4) * 8;
    const _Float16* wl_l = wlo + (size_t)(co0 + lanelo) * 64 + (lane >> 4) * 8;
    const char* xs0 = (const char*)(&xs[0][0]);
    const char* xs1 = (const char*)(&xs[1][0]);

    #pragma unroll 3
    for (int t = 0; t < 9; ++t) {
        const int dy = t / 3, dx = t % 3;
        unsigned rb[2], sz[2];
        #pragma unroll
        for (int pf = 0; pf < 2; ++pf) {
            const int px1 = pf * 16 + lanelo + dx;      // 0..33, in bounds
            rb[pf] = (unsigned)(dy * 34 + px1) * 128;   // 128B per px row
            sz[pf] = ((unsigned)px1 & 7) << 4;          // T2 XOR swizzle
        }
        #pragma unroll
        for (int cs = 0; cs < 2; ++cs) {                // ci0 = cs*32, K=32/step
            const half8 ah0 = *(const half8*)(wh_l + t * 8192 + 0 * 1024 + cs * 32);
            const half8 ah1 = *(const half8*)(wh_l + t * 8192 + 1 * 1024 + cs * 32);
            const half8 al0 = *(const half8*)(wl_l + t * 8192 + 0 * 1024 + cs * 32);
            const half8 al1 = *(const half8*)(wl_l + t * 8192 + 1 * 1024 + cs * 32);
            #pragma unroll
            for (int pf = 0; pf < 2; ++pf) {
                const unsigned ob = rb[pf] + (((unsigned)cs * 64 + kg2) ^ sz[pf]);
                const half8 bh = *(const half8*)(xs0 + ob);
                const half8 bl = *(const half8*)(xs1 + ob);
                acc[0][pf] = __builtin_amdgcn_mfma_f32_16x16x32_f16(ah0, bh, acc[0][pf], 0, 0, 0);
                acc[0][pf] = __builtin_amdgcn_mfma_f32_16x16x32_f16(ah0, bl, acc[0][pf], 0, 0, 0);
                acc[0][pf] = __builtin_amdgcn_mfma_f32_16x16x32_f16(al0, bh, acc[0][pf], 0, 0, 0);
                acc[1][pf] = __builtin_amdgcn_mfma_f32_16x16x32_f16(ah1, bh, acc[1][pf], 0, 0, 0);
                acc[1][pf] = __builtin_amdgcn_mfma_f32_16x16x32_f16(ah1, bl, acc[1][pf], 0, 0, 0);
                acc[1][pf] = __builtin_amdgcn_mfma_f32_16x16x32_f16(al1, bh, acc[1][pf], 0, 0, 0);
            }
        }
    }

    // ---- epilogue: LIF + multi-threshold spike + borderline flagging ----
    const float beta = beta_p[0];
    const float omb  = 1.0f - beta;

    #pragma unroll
    for (int cf = 0; cf < 2; ++cf) {
        #pragma unroll
        for (int pf = 0; pf < 2; ++pf) {
            const int px = px0 + pf * 16 + lanelo;
            #pragma unroll
            for (int r = 0; r < 4; ++r) {
                const int co = co0 + cf * 16 + (lane >> 4) * 4 + r;
                const size_t idx = (((size_t)n * COc + co) * HHc + y) * WWc + px;
                const float nm   = fmaf(mem[idx], beta, acc[cf][pf][r] * omb);
                const float mthr = fmaf(nm, rnormf[co], -bias[co]);
                const int s = (mthr > 0.f) + (mthr > 1.f) + (mthr > 2.f) + (mthr > 3.f);
                out_spk[idx] = (float)s;
                out_mem[idx] = (s > 0) ? 0.0f : nm;

                const bool fl = (fabsf(mthr) < EPSB) | (fabsf(mthr - 1.f) < EPSB) |
                                (fabsf(mthr - 2.f) < EPSB) | (fabsf(mthr - 3.f) < EPSB);
                const unsigned long long msk = __ballot(fl);
                if (msk) {
                    unsigned wb = 0;
                    if (lane == 0) wb = atomicAdd(counter, (unsigned)__popcll(msk));
                    wb = __shfl(wb, 0);
                    if (fl) {
                        const unsigned pos =
                            wb + (unsigned)__popcll(msk & ((1ull << lane) - 1ull));
                        if (pos < CAPc) list[pos] = (unsigned)idx;
                    }
                }
            }
        }
    }
}

// ---- Pass B: exact fp64 recompute of flagged pixels (wave per pixel, lane=ci) ----
__global__ __launch_bounds__(256) void fixB(
    const float* __restrict__ x, const float* __restrict__ mem,
    const float* __restrict__ beta_p, const float* __restrict__ bias,
    const double* __restrict__ normd, const double* __restrict__ wdT,
    const unsigned* __restrict__ counter, const unsigned* __restrict__ list,
    float* __restrict__ out_spk, float* __restrict__ out_mem)
{
    const int lane  = threadIdx.x & 63;
    const int wave  = blockIdx.x * 4 + (threadIdx.x >> 6);
    const int nwave = gridDim.x * 4;
    const unsigned cnt = min(counter[0], CAPc);
    const double beta = (double)beta_p[0];
    const double omb  = 1.0 - beta;

    for (unsigned p = wave; p < cnt; p += nwave) {
        const unsigned idx = list[p];
        const int xp = idx & 63, yp = (idx >> 6) & 63;
        const int co = (idx >> 12) & 127, n = idx >> 19;

        const float*  xc = x + ((size_t)n * CIc + lane) * (HHc * WWc);
        const double* wt = wdT + (size_t)co * 9 * CIc + lane;

        double a = 0.0;
        #pragma unroll
        for (int t = 0; t < 9; ++t) {
            const int yy = yp + t / 3 - 1, xx = xp + t % 3 - 1;
            const bool v = ((unsigned)yy < 64u) && ((unsigned)xx < 64u);
            const int yyc = min(max(yy, 0), 63), xxc = min(max(xx, 0), 63);
            const double xv = v ? (double)xc[yyc * WWc + xxc] : 0.0;
            a = fma(xv, wt[t * CIc], a);
        }
        #pragma unroll
        for (int off = 32; off; off >>= 1) a += __shfl_xor(a, off);

        if (lane == 0) {
            const double nm   = (double)mem[idx] * beta + a * omb;
            const double mthr = nm / normd[co] - (double)bias[co];
            const int s = (mthr > 0.) + (mthr > 1.) + (mthr > 2.) + (mthr > 3.);
            out_spk[idx] = (float)s;
            out_mem[idx] = (s > 0) ? 0.0f : (float)nm;
        }
    }
}

// ---- Fallback (ws too small): all-fp64 direct conv ----
__global__ __launch_bounds__(256) void conv_fp64_fb(
    const float* __restrict__ x, const float* __restrict__ mem,
    const float* __restrict__ w, const float* __restrict__ beta_p,
    const float* __restrict__ bias, const double* __restrict__ normd,
    float* __restrict__ out_spk, float* __restrict__ out_mem)
{
    const int ix = threadIdx.x, iy = blockIdx.x * 4 + threadIdx.y;
    const int co0 = blockIdx.y * 8, n = blockIdx.z;
    bool valid[9]; int xoff[9];
    #pragma unroll
    for (int kh = 0; kh < 3; ++kh) {
        const int yy = iy + kh - 1;
        #pragma unroll
        for (int kw = 0; kw < 3; ++kw) {
            const int xx = ix + kw - 1, t = kh * 3 + kw;
            valid[t] = ((unsigned)yy < 64u) && ((unsigned)xx < 64u);
            xoff[t]  = yy * WWc + xx;
        }
    }
    double acc[8];
    #pragma unroll
    for (int j = 0; j < 8; ++j) acc[j] = 0.0;
    const float* xb = x + (size_t)n * CIc * HHc * WWc;
    for (int ci = 0; ci < CIc; ++ci) {
        const float* xc = xb + (size_t)ci * HHc * WWc;
        #pragma unroll
        for (int t = 0; t < 9; ++t) {
            const double xv = valid[t] ? (double)xc[xoff[t]] : 0.0;
            const float* wt = w + ((size_t)t * CIc + ci) * COc + co0;
            #pragma unroll
            for (int j = 0; j < 8; ++j) acc[j] = fma(xv, (double)wt[j], acc[j]);
        }
    }
    const double beta = (double)beta_p[0], omb = 1.0 - beta;
    const size_t base = (((size_t)n * COc + co0) * HHc + iy) * WWc + ix;
    #pragma unroll
    for (int j = 0; j < 8; ++j) {
        const size_t idx = base + (size_t)j * (HHc * WWc);
        const double nm   = (double)mem[idx] * beta + acc[j] * omb;
        const double mthr = nm / normd[co0 + j] - (double)bias[co0 + j];
        const int s = (mthr > 0.) + (mthr > 1.) + (mthr > 2.) + (mthr > 3.);
        out_spk[idx] = (float)s;
        out_mem[idx] = (s > 0) ? 0.0f : (float)nm;
    }
}

extern "C" void kernel_launch(void* const* d_in, const int* in_sizes, int n_in,
                              void* d_out, int out_size, void* d_ws, size_t ws_size,
                              hipStream_t stream) {
    const float* x      = (const float*)d_in[0];
    const float* mem    = (const float*)d_in[1];
    const float* w      = (const float*)d_in[2];
    const float* beta_p = (const float*)d_in[3];
    const float* bias   = (const float*)d_in[4];

    float* out_spk = (float*)d_out;
    float* out_mem = out_spk + (size_t)NBc * COc * HHc * WWc;

    char* ws = (char*)d_ws;
    unsigned* counter = (unsigned*)(ws + O_CNT);
    double*   normd   = (double*)(ws + O_NORMD);
    float*    rnormf  = (float*)(ws + O_RNORM);
    double*   wdT     = (double*)(ws + O_WDT);
    _Float16* whi     = (_Float16*)(ws + O_WHI);
    _Float16* wlo     = (_Float16*)(ws + O_WLO);
    unsigned* list    = (unsigned*)(ws + O_LIST);

    if (ws_size >= WS_NEED) {
        prep_kernel<<<128 + 288, 256, 0, stream>>>(w, normd, rnormf, wdT, whi, wlo,
                                                   counter);
        dim3 grdM(HHc, 2, NBc);            // 64 y x 2 W-halves x 32 n = 4096 blocks
        convM<<<grdM, 256, 0, stream>>>(x, mem, whi, wlo, beta_p, bias, rnormf,
                                        out_spk, out_mem, counter, list);
        fixB<<<512, 256, 0, stream>>>(x, mem, beta_p, bias, normd, wdT,
                                      counter, list, out_spk, out_mem);
    } else {
        prep_kernel<<<128, 256, 0, stream>>>(w, normd, rnormf, wdT, nullptr, nullptr,
                                             counter);
        dim3 blk(WWc, 4, 1);
        dim3 grd(HHc / 4, COc / 8, NBc);
        conv_fp64_fb<<<grd, blk, 0, stream>>>(x, mem, w, beta_p, bias, normd,
                                              out_spk, out_mem);
    }
}

// Round 4
// 412.912 us; speedup vs baseline: 1.1788x; 1.1727x over previous
//
#include <hip/hip_runtime.h>

// SparseSpikingConv2D — Round 10: weight-stationary registers + row streaming.
// R9 post-mortem: occupancy 29.5->59% with NO throughput change (MfmaUtil ~9%
// both) -> shared invisible bottleneck: per-wave L2/L3 weight re-fetch (R7
// 0.6 GB, R9 1.2 GB; L2 thrashed by 134 MB write stream; FETCH_SIZE doesn't
// count L3 hits) + dependent load->MFMA chains at 40 VGPR ILP.
// R10: each wave holds its 16-cout weight slice in 72 VGPRs (loaded once per
// block); block = 64 co x 64 px, streams 8 rows via 4-slot LDS ring (67.6 KB,
// 2 blocks/CU, 1 barrier/row). Weight traffic 1.2 GB -> 75 MB; inner loop is
// pure ds_read->MFMA. mem[] prefetched under the MFMA loop (vmcnt-only, T14).
// Per-acc MFMA order identical to R7/R9 -> bitwise-same results + flag set.

typedef _Float16 half8 __attribute__((ext_vector_type(8)));
typedef float f32x4 __attribute__((ext_vector_type(4)));

constexpr int CIc = 64, COc = 128, HHc = 64, WWc = 64, NBc = 32;
constexpr float EPSB = 2e-4f;        // borderline band on mthr
constexpr unsigned CAPc = 1u << 18;  // fixup list capacity (~13K observed)

// workspace layout (bytes)
constexpr size_t O_CNT   = 0;                    // 1 uint (padded 16)
constexpr size_t O_NORMD = 16;                   // 128 double
constexpr size_t O_RNORM = O_NORMD + 1024;       // 128 float
constexpr size_t O_WDT   = O_RNORM + 512;        // [co][t][ci] double = 589824 B
constexpr size_t O_WHI   = O_WDT + 589824;       // [t][co][ci] fp16 hi = 147456 B
constexpr size_t O_WLO   = O_WHI + 147456;       // [t][co][ci] fp16 lo = 147456 B
constexpr size_t O_LIST  = O_WLO + 147456;       // CAPc uint
constexpr size_t WS_NEED = O_LIST + (size_t)CAPc * 4;   // ~1.85 MB

// Fused prep: blocks 0..127 -> norm (co=bx, 64-lane fp64 butterfly);
// blocks 128..415 -> wdT (fp64, for fixB) + whi/wlo (fp16 split, for convM).
__global__ void prep_kernel(const float* __restrict__ w, double* __restrict__ normd,
                            float* __restrict__ rnormf, double* __restrict__ wdT,
                            _Float16* __restrict__ whi, _Float16* __restrict__ wlo,
                            unsigned* __restrict__ counter) {
    const int bx = blockIdx.x;
    if (bx < 128) {
        const int co = bx, lane = threadIdx.x & 63;
        if (threadIdx.x >= 64) return;
        double s = 0.0;
        #pragma unroll
        for (int k = 0; k < 9; ++k) {
            const double v = (double)w[(k * 64 + lane) * COc + co];
            s = fma(v, v, s);
        }
        #pragma unroll
        for (int off = 32; off; off >>= 1) s += __shfl_xor(s, off);
        if (lane == 0) {
            s += 1e-8;
            normd[co]  = s;
            rnormf[co] = (float)(1.0 / s);
            if (co == 0) counter[0] = 0u;
        }
    } else {
        const int i = (bx - 128) * 256 + threadIdx.x;  // over 73728
        if (i >= 9 * CIc * COc) return;
        const int ci = i & 63, t = (i >> 6) % 9, co = i / (9 * 64);
        const float v = w[(t * CIc + ci) * COc + co];
        wdT[i] = (double)v;                            // wdT[co][t][ci]
        if (whi) {
            const int i2 = (t * COc + co) * CIc + ci;  // [t][co][ci]
            const _Float16 h = (_Float16)v;
            whi[i2] = h;
            wlo[i2] = (_Float16)(v - (float)h);
        }
    }
}

// ---- Pass A (MFMA, weight-stationary): 64 co x 64 px x 8 streamed rows ----
// Block = 256 thr = 4 waves; wave wv owns couts [co0, co0+16), co0 =
// cohalf*64 + wv*16, holding that slice's weights in 72 VGPRs (wH/wL[9][2]).
// 4-slot LDS row ring, slot(r) = r&3; per row: stage(y+2) -> mem prefetch ->
// 144 ds_read + 216 MFMA -> epilogue -> barrier. Grid (8,2,32) = 512 blocks.
// B-frag swizzle: byte ^= (px1&7)<<4 on BOTH write and read (unchanged).
// D: row=co=(lane>>4)*4+r, col=px=lane&15 (m89 layout, unchanged).
__global__ __launch_bounds__(256, 2) void convM(
    const float* __restrict__ x,       // [32,64,64,64]
    const float* __restrict__ mem,     // [32,128,64,64]
    const _Float16* __restrict__ whi,  // [9,128,64]
    const _Float16* __restrict__ wlo,  // [9,128,64]
    const float* __restrict__ beta_p,
    const float* __restrict__ bias,
    const float* __restrict__ rnormf,
    float* __restrict__ out_spk, float* __restrict__ out_mem,
    unsigned* __restrict__ counter, unsigned* __restrict__ list)
{
    // 4 slots x [hi 8448 B | lo 8448 B]; slot stride 16896 B; total 67584 B.
    __shared__ half8 xs[4224];
    char* xsb = (char*)(&xs[0]);

    const int tid = threadIdx.x;
    const int y0 = blockIdx.x * 8;
    const int cohalf = blockIdx.y;
    const int n = blockIdx.z;

    const int lane   = tid & 63;
    const int wv     = tid >> 6;
    const int co0    = cohalf * 64 + wv * 16;
    const int lanelo = lane & 15;
    const int kgi    = (lane >> 4) * 8;                 // ci sub-offset (elems)
    const unsigned kg2 = (unsigned)(lane >> 4) * 16;    // ci sub-offset (bytes)

    // ---- weights -> registers (once per block; static-indexed, rule #20) ----
    half8 wH[9][2], wL[9][2];
    {
        const int co = co0 + lanelo;
        const _Float16* wh = whi + (size_t)co * CIc + kgi;
        const _Float16* wl = wlo + (size_t)co * CIc + kgi;
        #pragma unroll
        for (int t = 0; t < 9; ++t)
            #pragma unroll
            for (int cs = 0; cs < 2; ++cs) {
                wH[t][cs] = *(const half8*)(wh + (size_t)t * COc * CIc + cs * 32);
                wL[t][cs] = *(const half8*)(wl + (size_t)t * COc * CIc + cs * 32);
            }
    }

    // ---- row staging: 528 items (8 cig x 66 px1); transient regs only ----
    auto stage = [&](int rabs) {
        const int slot = (rabs + 8) & 3;
        char* sb = xsb + slot * 16896;
        float v[3][8];
        #pragma unroll
        for (int c = 0; c < 3; ++c) {              // issue all loads first
            const int it = tid + c * 256;
            if (it < 528) {
                const int px1 = it % 66, cig = it / 66;
                const int px = px1 - 1;
                const bool val = ((unsigned)px < 64u) && ((unsigned)rabs < 64u);
                const float* xp = x + (((size_t)n * CIc + cig * 8) * HHc
                                       + (val ? rabs : 0)) * WWc + (val ? px : 0);
                #pragma unroll
                for (int j = 0; j < 8; ++j)
                    v[c][j] = val ? xp[j * (HHc * WWc)] : 0.0f;
            }
        }
        #pragma unroll
        for (int c = 0; c < 3; ++c) {              // convert + LDS write
            const int it = tid + c * 256;
            if (it < 528) {
                const int px1 = it % 66, cig = it / 66;
                half8 hv, lv;
                #pragma unroll
                for (int j = 0; j < 8; ++j) {
                    const float f = v[c][j];
                    const _Float16 h = (_Float16)f;
                    hv[j] = h;
                    lv[j] = (_Float16)(f - (float)h);
                }
                const unsigned off = (unsigned)px1 * 128
                                   + (((unsigned)cig * 16) ^ (((unsigned)px1 & 7) << 4));
                *(half8*)(sb + off)        = hv;
                *(half8*)(sb + 8448 + off) = lv;
            }
        }
    };

    // ---- prologue: rows y0-1, y0, y0+1 -> slots (r&3); distinct mod 4 ----
    stage(y0 - 1);
    stage(y0);
    stage(y0 + 1);
    __syncthreads();

    const float beta = beta_p[0];
    const float omb  = 1.0f - beta;
    float rnv[4], biv[4];
    #pragma unroll
    for (int r = 0; r < 4; ++r) {
        const int co = co0 + (lane >> 4) * 4 + r;
        rnv[r] = rnormf[co];
        biv[r] = bias[co];
    }

    for (int j = 0; j < 8; ++j) {
        const int y = y0 + j;

        // stage row y+2 into the retired slot (disjoint from compute's slots)
        if (j < 7) stage(y + 2);

        // mem[] prefetch: issued now, consumed after MFMA loop (vmcnt-only)
        float mv[4][4];
        #pragma unroll
        for (int r = 0; r < 4; ++r) {
            const int co = co0 + (lane >> 4) * 4 + r;
            const float* mp = mem + (((size_t)n * COc + co) * HHc + y) * WWc + lanelo;
            #pragma unroll
            for (int pf = 0; pf < 4; ++pf) mv[r][pf] = mp[pf * 16];
        }

        // ---- MFMA main loop: pure ds_read -> MFMA (order identical to R7) ----
        f32x4 acc[4];
        #pragma unroll
        for (int pf = 0; pf < 4; ++pf) acc[pf] = f32x4{0.f, 0.f, 0.f, 0.f};

        #pragma unroll
        for (int t = 0; t < 9; ++t) {
            const int dy = t / 3, dx = t % 3;
            const unsigned sbase = (unsigned)((y - 1 + dy + 8) & 3) * 16896;
            #pragma unroll
            for (int cs = 0; cs < 2; ++cs) {
                #pragma unroll
                for (int pf = 0; pf < 4; ++pf) {
                    const int px1 = pf * 16 + lanelo + dx;
                    const unsigned ob = sbase + (unsigned)px1 * 128
                        + (((unsigned)(cs * 64) + kg2) ^ (((unsigned)px1 & 7) << 4));
                    const half8 bh = *(const half8*)(xsb + ob);
                    const half8 bl = *(const half8*)(xsb + 8448 + ob);
                    acc[pf] = __builtin_amdgcn_mfma_f32_16x16x32_f16(wH[t][cs], bh, acc[pf], 0, 0, 0);
                    acc[pf] = __builtin_amdgcn_mfma_f32_16x16x32_f16(wH[t][cs], bl, acc[pf], 0, 0, 0);
                    acc[pf] = __builtin_amdgcn_mfma_f32_16x16x32_f16(wL[t][cs], bh, acc[pf], 0, 0, 0);
                }
            }
        }

        // ---- epilogue: LIF + spike + borderline flagging (mv in flight) ----
        #pragma unroll
        for (int pf = 0; pf < 4; ++pf) {
            const int px = pf * 16 + lanelo;
            #pragma unroll
            for (int r = 0; r < 4; ++r) {
                const int co = co0 + (lane >> 4) * 4 + r;
                const size_t idx = (((size_t)n * COc + co) * HHc + y) * WWc + px;
                const float nm   = fmaf(mv[r][pf], beta, acc[pf][r] * omb);
                const float mthr = fmaf(nm, rnv[r], -biv[r]);
                const int s = (mthr > 0.f) + (mthr > 1.f) + (mthr > 2.f) + (mthr > 3.f);
                out_spk[idx] = (float)s;
                out_mem[idx] = (s > 0) ? 0.0f : nm;

                const bool fl = (fabsf(mthr) < EPSB) | (fabsf(mthr - 1.f) < EPSB) |
                                (fabsf(mthr - 2.f) < EPSB) | (fabsf(mthr - 3.f) < EPSB);
                const unsigned long long msk = __ballot(fl);
                if (msk) {
                    unsigned wb = 0;
                    if (lane == 0) wb = atomicAdd(counter, (unsigned)__popcll(msk));
                    wb = __shfl(wb, 0);
                    if (fl) {
                        const unsigned pos =
                            wb + (unsigned)__popcll(msk & ((1ull << lane) - 1ull));
                        if (pos < CAPc) list[pos] = (unsigned)idx;
                    }
                }
            }
        }

        __syncthreads();   // row boundary: stage writes + LDS reads retire
    }
}

// ---- Pass B: exact fp64 recompute of flagged pixels (wave per pixel, lane=ci) ----
__global__ __launch_bounds__(256) void fixB(
    const float* __restrict__ x, const float* __restrict__ mem,
    const float* __restrict__ beta_p, const float* __restrict__ bias,
    const double* __restrict__ normd, const double* __restrict__ wdT,
    const unsigned* __restrict__ counter, const unsigned* __restrict__ list,
    float* __restrict__ out_spk, float* __restrict__ out_mem)
{
    const int lane  = threadIdx.x & 63;
    const int wave  = blockIdx.x * 4 + (threadIdx.x >> 6);
    const int nwave = gridDim.x * 4;
    const unsigned cnt = min(counter[0], CAPc);
    const double beta = (double)beta_p[0];
    const double omb  = 1.0 - beta;

    for (unsigned p = wave; p < cnt; p += nwave) {
        const unsigned idx = list[p];
        const int xp = idx & 63, yp = (idx >> 6) & 63;
        const int co = (idx >> 12) & 127, n = idx >> 19;

        const float*  xc = x + ((size_t)n * CIc + lane) * (HHc * WWc);
        const double* wt = wdT + (size_t)co * 9 * CIc + lane;

        double a = 0.0;
        #pragma unroll
        for (int t = 0; t < 9; ++t) {
            const int yy = yp + t / 3 - 1, xx = xp + t % 3 - 1;
            const bool v = ((unsigned)yy < 64u) && ((unsigned)xx < 64u);
            const int yyc = min(max(yy, 0), 63), xxc = min(max(xx, 0), 63);
            const double xv = v ? (double)xc[yyc * WWc + xxc] : 0.0;
            a = fma(xv, wt[t * CIc], a);
        }
        #pragma unroll
        for (int off = 32; off; off >>= 1) a += __shfl_xor(a, off);

        if (lane == 0) {
            const double nm   = (double)mem[idx] * beta + a * omb;
            const double mthr = nm / normd[co] - (double)bias[co];
            const int s = (mthr > 0.) + (mthr > 1.) + (mthr > 2.) + (mthr > 3.);
            out_spk[idx] = (float)s;
            out_mem[idx] = (s > 0) ? 0.0f : (float)nm;
        }
    }
}

// ---- Fallback (ws too small): all-fp64 direct conv ----
__global__ __launch_bounds__(256) void conv_fp64_fb(
    const float* __restrict__ x, const float* __restrict__ mem,
    const float* __restrict__ w, const float* __restrict__ beta_p,
    const float* __restrict__ bias, const double* __restrict__ normd,
    float* __restrict__ out_spk, float* __restrict__ out_mem)
{
    const int ix = threadIdx.x, iy = blockIdx.x * 4 + threadIdx.y;
    const int co0 = blockIdx.y * 8, n = blockIdx.z;
    bool valid[9]; int xoff[9];
    #pragma unroll
    for (int kh = 0; kh < 3; ++kh) {
        const int yy = iy + kh - 1;
        #pragma unroll
        for (int kw = 0; kw < 3; ++kw) {
            const int xx = ix + kw - 1, t = kh * 3 + kw;
            valid[t] = ((unsigned)yy < 64u) && ((unsigned)xx < 64u);
            xoff[t]  = yy * WWc + xx;
        }
    }
    double acc[8];
    #pragma unroll
    for (int j = 0; j < 8; ++j) acc[j] = 0.0;
    const float* xb = x + (size_t)n * CIc * HHc * WWc;
    for (int ci = 0; ci < CIc; ++ci) {
        const float* xc = xb + (size_t)ci * HHc * WWc;
        #pragma unroll
        for (int t = 0; t < 9; ++t) {
            const double xv = valid[t] ? (double)xc[xoff[t]] : 0.0;
            const float* wt = w + ((size_t)t * CIc + ci) * COc + co0;
            #pragma unroll
            for (int j = 0; j < 8; ++j) acc[j] = fma(xv, (double)wt[j], acc[j]);
        }
    }
    const double beta = (double)beta_p[0], omb = 1.0 - beta;
    const size_t base = (((size_t)n * COc + co0) * HHc + iy) * WWc + ix;
    #pragma unroll
    for (int j = 0; j < 8; ++j) {
        const size_t idx = base + (size_t)j * (HHc * WWc);
        const double nm   = (double)mem[idx] * beta + acc[j] * omb;
        const double mthr = nm / normd[co0 + j] - (double)bias[co0 + j];
        const int s = (mthr > 0.) + (mthr > 1.) + (mthr > 2.) + (mthr > 3.);
        out_spk[idx] = (float)s;
        out_mem[idx] = (s > 0) ? 0.0f : (float)nm;
    }
}

extern "C" void kernel_launch(void* const* d_in, const int* in_sizes, int n_in,
                              void* d_out, int out_size, void* d_ws, size_t ws_size,
                              hipStream_t stream) {
    const float* x      = (const float*)d_in[0];
    const float* mem    = (const float*)d_in[1];
    const float* w      = (const float*)d_in[2];
    const float* beta_p = (const float*)d_in[3];
    const float* bias   = (const float*)d_in[4];

    float* out_spk = (float*)d_out;
    float* out_mem = out_spk + (size_t)NBc * COc * HHc * WWc;

    char* ws = (char*)d_ws;
    unsigned* counter = (unsigned*)(ws + O_CNT);
    double*   normd   = (double*)(ws + O_NORMD);
    float*    rnormf  = (float*)(ws + O_RNORM);
    double*   wdT     = (double*)(ws + O_WDT);
    _Float16* whi     = (_Float16*)(ws + O_WHI);
    _Float16* wlo     = (_Float16*)(ws + O_WLO);
    unsigned* list    = (unsigned*)(ws + O_LIST);

    if (ws_size >= WS_NEED) {
        prep_kernel<<<128 + 288, 256, 0, stream>>>(w, normd, rnormf, wdT, whi, wlo,
                                                   counter);
        dim3 grdM(8, 2, NBc);              // 8 y-stripes x 2 co-halves x 32 n = 512
        convM<<<grdM, 256, 0, stream>>>(x, mem, whi, wlo, beta_p, bias, rnormf,
                                        out_spk, out_mem, counter, list);
        fixB<<<512, 256, 0, stream>>>(x, mem, beta_p, bias, normd, wdT,
                                      counter, list, out_spk, out_mem);
    } else {
        prep_kernel<<<128, 256, 0, stream>>>(w, normd, rnormf, wdT, nullptr, nullptr,
                                             counter);
        dim3 blk(WWc, 4, 1);
        dim3 grd(HHc / 4, COc / 8, NBc);
        conv_fp64_fb<<<grd, blk, 0, stream>>>(x, mem, w, beta_p, bias, normd,
                                              out_spk, out_mem);
    }
}

// Round 5
// 354.367 us; speedup vs baseline: 1.3735x; 1.1652x over previous
//
#include <hip/hip_runtime.h>

// SparseSpikingConv2D — Round 11: make prefetches survive the row barrier.
// R10 post-mortem: convM 187 us, MfmaUtil 12.5 / VALU 12.8 / HBM 14% -> ~75%
// stall. Cause 1: __syncthreads() drains vmcnt(0) every row (compiler emits
// s_waitcnt vmcnt(0) lgkmcnt(0) before s_barrier), killing any cross-row
// prefetch and exposing stage+store latency x8 rows in lockstep. Cause 2:
// epilogue VALU bloat (16 ballots + 11-op spike/flag math per output; ~400
// VALU/thread/row, confirmed by VALUBusy arithmetic).
// R11: raw s_barrier with lgkmcnt(0)-only drain (LDS ring only needs LDS
// visibility; reg-destined loads + global stores legally cross); issue-early/
// write-late x staging (xr regs, 1-row cover, survives barrier); epilogue via
// ceil/clamp spike + rint flag + per-thread flag mask with 1-ballot fast path;
// EPSB 2e-4 -> 5e-5 (25x margin over ~2e-6 worst-case mthr error) -> fixB ~4x
// less work; s_setprio around MFMA. MFMA order unchanged -> conv bit-identical.

typedef _Float16 half8 __attribute__((ext_vector_type(8)));
typedef float f32x4 __attribute__((ext_vector_type(4)));

constexpr int CIc = 64, COc = 128, HHc = 64, WWc = 64, NBc = 32;
constexpr float EPSB = 5e-5f;        // borderline band on mthr (err ~2e-6)
constexpr unsigned CAPc = 1u << 18;  // fixup list capacity

// workspace layout (bytes)
constexpr size_t O_CNT   = 0;                    // 1 uint (padded 16)
constexpr size_t O_NORMD = 16;                   // 128 double
constexpr size_t O_RNORM = O_NORMD + 1024;       // 128 float
constexpr size_t O_WDT   = O_RNORM + 512;        // [co][t][ci] double = 589824 B
constexpr size_t O_WHI   = O_WDT + 589824;       // [t][co][ci] fp16 hi = 147456 B
constexpr size_t O_WLO   = O_WHI + 147456;       // [t][co][ci] fp16 lo = 147456 B
constexpr size_t O_LIST  = O_WLO + 147456;       // CAPc uint
constexpr size_t WS_NEED = O_LIST + (size_t)CAPc * 4;   // ~1.85 MB

// Fused prep: blocks 0..127 -> norm (co=bx, 64-lane fp64 butterfly);
// blocks 128..415 -> wdT (fp64, for fixB) + whi/wlo (fp16 split, for convM).
__global__ void prep_kernel(const float* __restrict__ w, double* __restrict__ normd,
                            float* __restrict__ rnormf, double* __restrict__ wdT,
                            _Float16* __restrict__ whi, _Float16* __restrict__ wlo,
                            unsigned* __restrict__ counter) {
    const int bx = blockIdx.x;
    if (bx < 128) {
        const int co = bx, lane = threadIdx.x & 63;
        if (threadIdx.x >= 64) return;
        double s = 0.0;
        #pragma unroll
        for (int k = 0; k < 9; ++k) {
            const double v = (double)w[(k * 64 + lane) * COc + co];
            s = fma(v, v, s);
        }
        #pragma unroll
        for (int off = 32; off; off >>= 1) s += __shfl_xor(s, off);
        if (lane == 0) {
            s += 1e-8;
            normd[co]  = s;
            rnormf[co] = (float)(1.0 / s);
            if (co == 0) counter[0] = 0u;
        }
    } else {
        const int i = (bx - 128) * 256 + threadIdx.x;  // over 73728
        if (i >= 9 * CIc * COc) return;
        const int ci = i & 63, t = (i >> 6) % 9, co = i / (9 * 64);
        const float v = w[(t * CIc + ci) * COc + co];
        wdT[i] = (double)v;                            // wdT[co][t][ci]
        if (whi) {
            const int i2 = (t * COc + co) * CIc + ci;  // [t][co][ci]
            const _Float16 h = (_Float16)v;
            whi[i2] = h;
            wlo[i2] = (_Float16)(v - (float)h);
        }
    }
}

// ---- Pass A (MFMA, pipelined weight-stationary): 64co x 64px x 8 rows ----
// Block = 256 thr = 4 waves; grid (8,2,32) = 512 blocks = 2/CU (LDS 67.6 KB).
// 4-slot LDS row ring; per row j: {ds_write staged row y+2 (xr, issued @j-1)}
// -> {issue xr loads for y+3} -> {mv prefetch} -> {MFMA (setprio 1)} ->
// {epilogue} -> {lgkmcnt(0); raw s_barrier} — vmcnt NOT drained, so xr/mv/
// store latency crosses the barrier. Swizzle byte^=(px1&7)<<4 write+read.
// D: row=co=(lane>>4)*4+r, col=px=lane&15. MFMA order identical to R7-R10.
__global__ __launch_bounds__(256, 2) void convM(
    const float* __restrict__ x,       // [32,64,64,64]
    const float* __restrict__ mem,     // [32,128,64,64]
    const _Float16* __restrict__ whi,  // [9,128,64]
    const _Float16* __restrict__ wlo,  // [9,128,64]
    const float* __restrict__ beta_p,
    const float* __restrict__ bias,
    const float* __restrict__ rnormf,
    float* __restrict__ out_spk, float* __restrict__ out_mem,
    unsigned* __restrict__ counter, unsigned* __restrict__ list)
{
    // 4 slots x [hi 8448 B | lo 8448 B]; slot stride 16896 B; total 67584 B.
    __shared__ half8 xs[4224];
    char* xsb = (char*)(&xs[0]);

    const int tid = threadIdx.x;
    const int y0 = blockIdx.x * 8;
    const int cohalf = blockIdx.y;
    const int n = blockIdx.z;

    const int lane   = tid & 63;
    const int wv     = tid >> 6;
    const int co0    = cohalf * 64 + wv * 16;
    const int lanelo = lane & 15;
    const int kgi    = (lane >> 4) * 8;                 // ci sub-offset (elems)
    const unsigned kg2 = (unsigned)(lane >> 4) * 16;    // ci sub-offset (bytes)

    // ---- weights -> registers (once per block; static-indexed) ----
    half8 wH[9][2], wL[9][2];
    {
        const int co = co0 + lanelo;
        const _Float16* wh = whi + (size_t)co * CIc + kgi;
        const _Float16* wl = wlo + (size_t)co * CIc + kgi;
        #pragma unroll
        for (int t = 0; t < 9; ++t)
            #pragma unroll
            for (int cs = 0; cs < 2; ++cs) {
                wH[t][cs] = *(const half8*)(wh + (size_t)t * COc * CIc + cs * 32);
                wL[t][cs] = *(const half8*)(wl + (size_t)t * COc * CIc + cs * 32);
            }
    }

    // ---- staging split: issue (global->xr regs) / write (xr->LDS), T14 ----
    float xr[3][8];   // in-flight x row; static-indexed only

    auto issueRow = [&](int rabs) {
        #pragma unroll
        for (int c = 0; c < 3; ++c) {
            const int it = tid + c * 256;
            if (it < 528) {
                const int px1 = it % 66, cig = it / 66;
                const int px = px1 - 1;
                const bool val = ((unsigned)px < 64u) && ((unsigned)rabs < 64u);
                const float* xp = x + (((size_t)n * CIc + cig * 8) * HHc
                                       + (val ? rabs : 0)) * WWc + (val ? px : 0);
                #pragma unroll
                for (int j2 = 0; j2 < 8; ++j2)
                    xr[c][j2] = val ? xp[j2 * (HHc * WWc)] : 0.0f;
            }
        }
    };
    auto writeRow = [&](int rabs) {
        const int slot = (rabs + 8) & 3;
        char* sb = xsb + slot * 16896;
        #pragma unroll
        for (int c = 0; c < 3; ++c) {
            const int it = tid + c * 256;
            if (it < 528) {
                const int px1 = it % 66, cig = it / 66;
                half8 hv, lv;
                #pragma unroll
                for (int j2 = 0; j2 < 8; ++j2) {
                    const float f = xr[c][j2];
                    const _Float16 h = (_Float16)f;
                    hv[j2] = h;
                    lv[j2] = (_Float16)(f - (float)h);
                }
                const unsigned off = (unsigned)px1 * 128
                                   + (((unsigned)cig * 16) ^ (((unsigned)px1 & 7) << 4));
                *(half8*)(sb + off)        = hv;
                *(half8*)(sb + 8448 + off) = lv;
            }
        }
    };

    // ---- prologue: rows y0-1..y0+1 staged; y0+2 left in flight in xr ----
    issueRow(y0 - 1); writeRow(y0 - 1);
    issueRow(y0);     writeRow(y0);
    issueRow(y0 + 1); writeRow(y0 + 1);
    issueRow(y0 + 2);
    asm volatile("s_waitcnt lgkmcnt(0)" ::: "memory");
    __builtin_amdgcn_s_barrier();

    const float beta = beta_p[0];
    const float omb  = 1.0f - beta;
    float rnv[4], biv[4];
    #pragma unroll
    for (int r = 0; r < 4; ++r) {
        const int co = co0 + (lane >> 4) * 4 + r;
        rnv[r] = rnormf[co];
        biv[r] = bias[co];
    }

    for (int j = 0; j < 8; ++j) {
        const int y = y0 + j;

        // write staged row y+2 (xr issued one row ago -> latency long covered);
        // slot (y+2)&3 = (y-2)&3, last read at row j-1 (barrier separates).
        if (j < 7) writeRow(y + 2);
        // refill xr for row y+3 (consumed next row; crosses the raw barrier)
        if (j < 6) issueRow(y + 3);

        // mem[] prefetch: consumed in epilogue (~3K cyc of MFMA cover)
        float mv[4][4];
        #pragma unroll
        for (int r = 0; r < 4; ++r) {
            const int co = co0 + (lane >> 4) * 4 + r;
            const float* mp = mem + (((size_t)n * COc + co) * HHc + y) * WWc + lanelo;
            #pragma unroll
            for (int pf = 0; pf < 4; ++pf) mv[r][pf] = mp[pf * 16];
        }

        // ---- MFMA main loop: pure ds_read -> MFMA (order identical) ----
        f32x4 acc[4];
        #pragma unroll
        for (int pf = 0; pf < 4; ++pf) acc[pf] = f32x4{0.f, 0.f, 0.f, 0.f};

        __builtin_amdgcn_s_setprio(1);
        #pragma unroll
        for (int t = 0; t < 9; ++t) {
            const int dy = t / 3, dx = t % 3;
            const unsigned sbase = (unsigned)((y - 1 + dy + 8) & 3) * 16896;
            #pragma unroll
            for (int cs = 0; cs < 2; ++cs) {
                #pragma unroll
                for (int pf = 0; pf < 4; ++pf) {
                    const int px1 = pf * 16 + lanelo + dx;
                    const unsigned ob = sbase + (unsigned)px1 * 128
                        + (((unsigned)(cs * 64) + kg2) ^ (((unsigned)px1 & 7) << 4));
                    const half8 bh = *(const half8*)(xsb + ob);
                    const half8 bl = *(const half8*)(xsb + 8448 + ob);
                    acc[pf] = __builtin_amdgcn_mfma_f32_16x16x32_f16(wH[t][cs], bh, acc[pf], 0, 0, 0);
                    acc[pf] = __builtin_amdgcn_mfma_f32_16x16x32_f16(wH[t][cs], bl, acc[pf], 0, 0, 0);
                    acc[pf] = __builtin_amdgcn_mfma_f32_16x16x32_f16(wL[t][cs], bh, acc[pf], 0, 0, 0);
                }
            }
        }
        __builtin_amdgcn_s_setprio(0);

        // ---- epilogue: LIF + spike + flag mask (1-ballot fast path) ----
        unsigned flm = 0u;
        #pragma unroll
        for (int pf = 0; pf < 4; ++pf) {
            const int px = pf * 16 + lanelo;
            #pragma unroll
            for (int r = 0; r < 4; ++r) {
                const int co = co0 + (lane >> 4) * 4 + r;
                const size_t idx = (((size_t)n * COc + co) * HHc + y) * WWc + px;
                const float nm   = fmaf(mv[r][pf], beta, acc[pf][r] * omb);
                const float mthr = fmaf(nm, rnv[r], -biv[r]);
                // s = (mthr>0)+(mthr>1)+(mthr>2)+(mthr>3) == clamp(ceil,0,4)
                const float cm = fminf(fmaxf(ceilf(mthr), 0.0f), 4.0f);
                out_spk[idx] = cm;
                out_mem[idx] = (cm > 0.0f) ? 0.0f : nm;
                // flag iff |mthr - d| < EPSB for some d in {0..3}; band << 0.5
                // so only the nearest integer can qualify.
                const float fr = rintf(mthr);
                const bool fl = (fabsf(mthr - fr) < EPSB) &
                                (fr >= 0.0f) & (fr <= 3.5f);
                flm |= ((unsigned)fl) << (pf * 4 + r);
            }
        }
        if (__ballot(flm != 0u)) {          // rare (~2% of wave-rows)
            #pragma unroll
            for (int pf = 0; pf < 4; ++pf) {
                #pragma unroll
                for (int r = 0; r < 4; ++r) {
                    const unsigned long long msk =
                        __ballot((flm >> (pf * 4 + r)) & 1u);
                    if (msk) {
                        unsigned wb = 0;
                        if (lane == 0)
                            wb = atomicAdd(counter, (unsigned)__popcll(msk));
                        wb = __shfl(wb, 0);
                        if ((flm >> (pf * 4 + r)) & 1u) {
                            const int px = pf * 16 + lanelo;
                            const int co = co0 + (lane >> 4) * 4 + r;
                            const size_t idx =
                                (((size_t)n * COc + co) * HHc + y) * WWc + px;
                            const unsigned pos = wb +
                                (unsigned)__popcll(msk & ((1ull << lane) - 1ull));
                            if (pos < CAPc) list[pos] = (unsigned)idx;
                        }
                    }
                }
            }
        }

        // row boundary: LDS writes/reads must retire; vmem stays in flight.
        asm volatile("s_waitcnt lgkmcnt(0)" ::: "memory");
        __builtin_amdgcn_s_barrier();
    }
}

// ---- Pass B: exact fp64 recompute of flagged pixels (wave per pixel, lane=ci) ----
__global__ __launch_bounds__(256) void fixB(
    const float* __restrict__ x, const float* __restrict__ mem,
    const float* __restrict__ beta_p, const float* __restrict__ bias,
    const double* __restrict__ normd, const double* __restrict__ wdT,
    const unsigned* __restrict__ counter, const unsigned* __restrict__ list,
    float* __restrict__ out_spk, float* __restrict__ out_mem)
{
    const int lane  = threadIdx.x & 63;
    const int wave  = blockIdx.x * 4 + (threadIdx.x >> 6);
    const int nwave = gridDim.x * 4;
    const unsigned cnt = min(counter[0], CAPc);
    const double beta = (double)beta_p[0];
    const double omb  = 1.0 - beta;

    for (unsigned p = wave; p < cnt; p += nwave) {
        const unsigned idx = list[p];
        const int xp = idx & 63, yp = (idx >> 6) & 63;
        const int co = (idx >> 12) & 127, n = idx >> 19;

        const float*  xc = x + ((size_t)n * CIc + lane) * (HHc * WWc);
        const double* wt = wdT + (size_t)co * 9 * CIc + lane;

        double a = 0.0;
        #pragma unroll
        for (int t = 0; t < 9; ++t) {
            const int yy = yp + t / 3 - 1, xx = xp + t % 3 - 1;
            const bool v = ((unsigned)yy < 64u) && ((unsigned)xx < 64u);
            const int yyc = min(max(yy, 0), 63), xxc = min(max(xx, 0), 63);
            const double xv = v ? (double)xc[yyc * WWc + xxc] : 0.0;
            a = fma(xv, wt[t * CIc], a);
        }
        #pragma unroll
        for (int off = 32; off; off >>= 1) a += __shfl_xor(a, off);

        if (lane == 0) {
            const double nm   = (double)mem[idx] * beta + a * omb;
            const double mthr = nm / normd[co] - (double)bias[co];
            const int s = (mthr > 0.) + (mthr > 1.) + (mthr > 2.) + (mthr > 3.);
            out_spk[idx] = (float)s;
            out_mem[idx] = (s > 0) ? 0.0f : (float)nm;
        }
    }
}

// ---- Fallback (ws too small): all-fp64 direct conv ----
__global__ __launch_bounds__(256) void conv_fp64_fb(
    const float* __restrict__ x, const float* __restrict__ mem,
    const float* __restrict__ w, const float* __restrict__ beta_p,
    const float* __restrict__ bias, const double* __restrict__ normd,
    float* __restrict__ out_spk, float* __restrict__ out_mem)
{
    const int ix = threadIdx.x, iy = blockIdx.x * 4 + threadIdx.y;
    const int co0 = blockIdx.y * 8, n = blockIdx.z;
    bool valid[9]; int xoff[9];
    #pragma unroll
    for (int kh = 0; kh < 3; ++kh) {
        const int yy = iy + kh - 1;
        #pragma unroll
        for (int kw = 0; kw < 3; ++kw) {
            const int xx = ix + kw - 1, t = kh * 3 + kw;
            valid[t] = ((unsigned)yy < 64u) && ((unsigned)xx < 64u);
            xoff[t]  = yy * WWc + xx;
        }
    }
    double acc[8];
    #pragma unroll
    for (int j = 0; j < 8; ++j) acc[j] = 0.0;
    const float* xb = x + (size_t)n * CIc * HHc * WWc;
    for (int ci = 0; ci < CIc; ++ci) {
        const float* xc = xb + (size_t)ci * HHc * WWc;
        #pragma unroll
        for (int t = 0; t < 9; ++t) {
            const double xv = valid[t] ? (double)xc[xoff[t]] : 0.0;
            const float* wt = w + ((size_t)t * CIc + ci) * COc + co0;
            #pragma unroll
            for (int j = 0; j < 8; ++j) acc[j] = fma(xv, (double)wt[j], acc[j]);
        }
    }
    const double beta = (double)beta_p[0], omb = 1.0 - beta;
    const size_t base = (((size_t)n * COc + co0) * HHc + iy) * WWc + ix;
    #pragma unroll
    for (int j = 0; j < 8; ++j) {
        const size_t idx = base + (size_t)j * (HHc * WWc);
        const double nm   = (double)mem[idx] * beta + acc[j] * omb;
        const double mthr = nm / normd[co0 + j] - (double)bias[co0 + j];
        const int s = (mthr > 0.) + (mthr > 1.) + (mthr > 2.) + (mthr > 3.);
        out_spk[idx] = (float)s;
        out_mem[idx] = (s > 0) ? 0.0f : (float)nm;
    }
}

extern "C" void kernel_launch(void* const* d_in, const int* in_sizes, int n_in,
                              void* d_out, int out_size, void* d_ws, size_t ws_size,
                              hipStream_t stream) {
    const float* x      = (const float*)d_in[0];
    const float* mem    = (const float*)d_in[1];
    const float* w      = (const float*)d_in[2];
    const float* beta_p = (const float*)d_in[3];
    const float* bias   = (const float*)d_in[4];

    float* out_spk = (float*)d_out;
    float* out_mem = out_spk + (size_t)NBc * COc * HHc * WWc;

    char* ws = (char*)d_ws;
    unsigned* counter = (unsigned*)(ws + O_CNT);
    double*   normd   = (double*)(ws + O_NORMD);
    float*    rnormf  = (float*)(ws + O_RNORM);
    double*   wdT     = (double*)(ws + O_WDT);
    _Float16* whi     = (_Float16*)(ws + O_WHI);
    _Float16* wlo     = (_Float16*)(ws + O_WLO);
    unsigned* list    = (unsigned*)(ws + O_LIST);

    if (ws_size >= WS_NEED) {
        prep_kernel<<<128 + 288, 256, 0, stream>>>(w, normd, rnormf, wdT, whi, wlo,
                                                   counter);
        dim3 grdM(8, 2, NBc);              // 8 y-stripes x 2 co-halves x 32 n = 512
        convM<<<grdM, 256, 0, stream>>>(x, mem, whi, wlo, beta_p, bias, rnormf,
                                        out_spk, out_mem, counter, list);
        fixB<<<512, 256, 0, stream>>>(x, mem, beta_p, bias, normd, wdT,
                                      counter, list, out_spk, out_mem);
    } else {
        prep_kernel<<<128, 256, 0, stream>>>(w, normd, rnormf, wdT, nullptr, nullptr,
                                             counter);
        dim3 blk(WWc, 4, 1);
        dim3 grd(HHc / 4, COc / 8, NBc);
        conv_fp64_fb<<<grd, blk, 0, stream>>>(x, mem, w, beta_p, bias, normd,
                                              out_spk, out_mem);
    }
}